// Round 18
// baseline (91.306 us; speedup 1.0000x reference)
//
#include <hip/hip_runtime.h>
#include <hip/hip_bf16.h>

typedef float f32x4 __attribute__((ext_vector_type(4)));
typedef _Float16 f16x8 __attribute__((ext_vector_type(8)));
typedef unsigned int u32;

#define SQ   2048
#define HQ   16
#define HKV  4
#define DH   128
#define WIN  1024
#define QT   64
#define KT   64
#define WROW 36

#define AS1 __attribute__((address_space(1)))
#define AS3 __attribute__((address_space(3)))

__device__ __forceinline__ void gload16(const void* g, void* l) {
  __builtin_amdgcn_global_load_lds((const AS1 u32*)g, (AS3 u32*)l, 16, 0, 0);
}

// fused wait+barrier (verified race-free in round 14)
#define BARW(N) do { __builtin_amdgcn_sched_barrier(0);                        \
  asm volatile("s_waitcnt vmcnt(" #N ")\n\ts_barrier" ::: "memory");           \
  __builtin_amdgcn_sched_barrier(0); } while (0)
#define BARP() do { __builtin_amdgcn_sched_barrier(0);                         \
  asm volatile("s_barrier" ::: "memory");                                      \
  __builtin_amdgcn_sched_barrier(0); } while (0)

#define PRIO1() __builtin_amdgcn_s_setprio(1)
#define PRIO0() __builtin_amdgcn_s_setprio(0)

// e = exp(30*tanh(s/sqrt(128)) - 30) == 2^(-86.5617/(2^(s*0.2550341)+1))
__device__ __forceinline__ float swa_e(float s) {
  float u = __builtin_amdgcn_exp2f(s * 0.2550341464f);
  return __builtin_amdgcn_exp2f(-86.5617025f * __builtin_amdgcn_rcpf(u + 1.0f));
}

// ---- prep: K -> kf f16 row-chunk-swizzled [b][hk][s][d];
//            V -> vt f16 [b][hk][t32][d][key32], chunk c stored at c^((d>>1)&3) ----
__global__ __launch_bounds__(256)
void prep(const float* __restrict__ K, const float* __restrict__ V,
          _Float16* __restrict__ kf, _Float16* __restrict__ vt)
{
  const int t = blockIdx.x * 256 + threadIdx.x;
  const int NK = 2 * HKV * SQ * 16;   // 262144 threads for K
  if (t < NK) {
    const int p  = t & 15;
    const int s  = (t >> 4) & (SQ - 1);
    const int hk = (t >> 15) & 3;
    const int b  = t >> 17;
    const int c  = p ^ (s & 7);
    const float* src = K + (((size_t)b * SQ + s) * HKV + hk) * DH + c * 8;
    f32x4 x0 = *(const f32x4*)src;
    f32x4 x1 = *(const f32x4*)(src + 4);
    f16x8 o;
    #pragma unroll
    for (int j = 0; j < 4; ++j) { o[j] = (_Float16)x0[j]; o[4 + j] = (_Float16)x1[j]; }
    *(f16x8*)(kf + (((size_t)(b * HKV + hk)) * SQ + s) * DH + p * 8) = o;
  } else {
    const int u   = t - NK;                 // 262144 threads for V
    const int p   = u & 3;                  // PHYSICAL 8-key chunk within 32
    const int d   = (u >> 2) & 127;
    const int t32 = (u >> 9) & 63;
    const int hk  = (u >> 15) & 3;
    const int b   = u >> 17;
    const int c   = p ^ ((d >> 1) & 3);     // logical chunk stored at physical p
    f16x8 o;
    #pragma unroll
    for (int j = 0; j < 8; ++j) {
      const int s = t32 * 32 + c * 8 + j;
      o[j] = (_Float16)V[(((size_t)b * SQ + s) * HKV + hk) * DH + d];
    }
    *(f16x8*)(vt + ((((size_t)(b * HKV + hk)) * 64 + t32) * DH + d) * 32 + p * 8) = o;
  }
}

__global__ __launch_bounds__(256, 4)
void swa_fwd(const float* __restrict__ Q, float* __restrict__ O,
             const _Float16* __restrict__ kf, const _Float16* __restrict__ vt)
{
  __shared__ _Float16 lbuf[16384];       // 32KB: ph1 = 2x16KB K; ph2 = K0,K1,V0,V1 x8KB
  __shared__ _Float16 lW[4][16 * WROW];  // 4.6KB

  const int tid  = threadIdx.x;
  const int lane = tid & 63;
  const int wv   = tid >> 6;             // 0..3
  const int lm   = lane & 15;
  const int lg   = lane >> 4;

  // ---- XCD-pinned, uniform-work bundles: grid 768 = 3 identical blocks/CU ----
  // per stream: j<64 -> heavy window qt=16+(j>>2) (17 tiles);
  //             j>=64 -> light PAIR (15-i, i), i=(j-64)>>2 (16-i + i+1 = 17 tiles)
  const int bid    = blockIdx.x;
  const int stream = bid & 7;
  const int b      = stream >> 2;
  const int hk     = stream & 3;
  const int j      = bid >> 3;           // 0..95
  int nw, qtv[2], hs;
  if (j < 64) {
    nw = 1; qtv[0] = 16 + (j >> 2); qtv[1] = 0; hs = j & 3;
  } else {
    const int u = j - 64;
    const int i = u >> 2;
    nw = 2; qtv[0] = 15 - i; qtv[1] = i; hs = u & 3;
  }
  const int h = hk * 4 + hs;

  const _Float16* kfb = kf + ((size_t)(b * HKV + hk)) * SQ * DH;
  const char*     vtb = (const char*)(vt + ((size_t)(b * HKV + hk)) * 64 * DH * 32);

  #define STAGE16K(dstb, src) do {                                           \
    _Pragma("unroll")                                                        \
    for (int r4 = 0; r4 < 4; ++r4)                                           \
      gload16((const char*)(src) + r4 * 4096 + wv * 1024 + lane * 16,        \
              (char*)lbuf + (dstb) + r4 * 4096 + wv * 1024);                 \
  } while (0)
  #define STAGE8K(dstb, src) do {                                            \
    _Pragma("unroll")                                                        \
    for (int r2 = 0; r2 < 2; ++r2)                                           \
      gload16((const char*)(src) + r2 * 4096 + wv * 1024 + lane * 16,        \
              (char*)lbuf + (dstb) + r2 * 4096 + wv * 1024);                 \
  } while (0)

  for (int w = 0; w < nw; ++w) {
    const int qt = qtv[w];
    const int q0 = qt * QT;

    // ---- Q fragments (A-layout): row=lm, k=lg*8+j per 32-wide kb ----
    f16x8 qa[4];
    {
      const int qrow = q0 + wv * 16 + lm;
      const float* qp = Q + (((size_t)b * SQ + qrow) * HQ + h) * DH;
      #pragma unroll
      for (int kb = 0; kb < 4; ++kb) {
        const float* p = qp + kb * 32 + lg * 8;
        f32x4 x0 = *(const f32x4*)p;
        f32x4 x1 = *(const f32x4*)(p + 4);
        f16x8 a;
        #pragma unroll
        for (int jj = 0; jj < 4; ++jj) { a[jj] = (_Float16)x0[jj]; a[4 + jj] = (_Float16)x1[jj]; }
        qa[kb] = a;
      }
    }

    const int kmin = (q0 - WIN) > 0 ? (q0 - WIN) : 0;   // multiple of 64
    const int nt   = (q0 + QT - kmin) / KT;             // 1..17
    const int qr0  = q0 + wv * 16 + lg * 4;

    // ============ phase 1: row sums Z (KT=64 K dbuf, counted-vmcnt) ====
    float zs[4] = {0.f, 0.f, 0.f, 0.f};
    {
      STAGE16K(0, kfb + (size_t)kmin * DH);               // 4 loads/wave
      if (nt > 1) {
        STAGE16K(16384, kfb + (size_t)(kmin + KT) * DH);  // +4
        BARW(4);                                          // t0 landed, t1 in flight
      } else {
        BARW(0);
      }
      for (int t = 0; t < nt; ++t) {
        const char* cur  = (const char*)lbuf + (t & 1) * 16384;
        const int  kbase = kmin + t * KT;
        const bool peel  = (t == 0 && q0 >= WIN) || (t == nt - 1);
        #pragma unroll
        for (int ks = 0; ks < 4; ++ks) {
          f32x4 acc = {0.f, 0.f, 0.f, 0.f};
          const int keyl = ks * 16 + lm;
          PRIO1();
          #pragma unroll
          for (int kb = 0; kb < 4; ++kb) {
            const int chunk = (kb * 4 + lg) ^ (keyl & 7);
            f16x8 bf = *(const f16x8*)(cur + keyl * 256 + chunk * 16);
            acc = __builtin_amdgcn_mfma_f32_16x16x32_f16(qa[kb], bf, acc, 0, 0, 0);
          }
          PRIO0();
          if (peel) {
            const int key = kbase + keyl;
            #pragma unroll
            for (int r = 0; r < 4; ++r) {
              const int qr = qr0 + r;
              const bool ok = (key <= qr) && (key >= qr - WIN);
              zs[r] += ok ? swa_e(acc[r]) : 0.f;
            }
          } else {
            #pragma unroll
            for (int r = 0; r < 4; ++r) zs[r] += swa_e(acc[r]);
          }
        }
        BARP();                                  // readers of buf(t&1) retired
        if (t + 2 < nt) {
          STAGE16K((t & 1) * 16384, kfb + (size_t)(kmin + (t + 2) * KT) * DH);
          BARW(4);                               // t+1 landed, t+2 in flight
        } else {
          BARW(0);                               // drain tail
        }
      }
    }

    // ---- Z reduce; rz = 1.06/Z; sthr = survivor threshold in s-space ----
    float rz[4], sthr[4];
    #pragma unroll
    for (int r = 0; r < 4; ++r) {
      float z = zs[r];
      z += __shfl_xor(z, 1);
      z += __shfl_xor(z, 2);
      z += __shfl_xor(z, 4);
      z += __shfl_xor(z, 8);
      rz[r] = 1.06f / z;
      float lt = __log2f(0.0283018868f * z);
      float A  = -86.5617024f / lt - 1.0f;
      float sv = 3.9204912f * __log2f(A) - 0.05f;   // conservative margin
      sv = (lt >= 0.f) ? 1e30f : sv;
      sv = (lt <= -86.5617f) ? -1e30f : sv;
      sthr[r] = sv;
    }

    // ====== phase 2: weights + PV, KT=32 K+V dbuf, counted-vmcnt ======
    // lbuf bytes: K0 @0, K1 @8192, V0 @16384, V1 @24576
    f32x4 oacc[8];
    #pragma unroll
    for (int ii = 0; ii < 8; ++ii) oacc[ii] = (f32x4){0.f, 0.f, 0.f, 0.f};

    const int nt2 = (q0 + QT - kmin) >> 5;   // 32-key sub-tiles, >= 2
    STAGE8K(0,     kfb + (size_t)kmin * DH);            // K0: 2 loads/wave
    STAGE8K(16384, vtb + (size_t)(kmin >> 5) * 8192);   // V0: 2
    if (nt2 > 1) {
      STAGE8K(8192,         kfb + (size_t)(kmin + 32) * DH);         // K1: 2
      STAGE8K(16384 + 8192, vtb + (size_t)((kmin >> 5) + 1) * 8192); // V1: 2
      BARW(4);                                 // t0's K+V landed, t1's in flight
    } else {
      BARW(0);
    }

    const int vpc = lg ^ ((lm >> 1) & 3);      // physical V chunk for this lane

    for (int t2 = 0; t2 < nt2; ++t2) {
      const char* curK = (const char*)lbuf + (t2 & 1) * 8192;
      const char* curV = (const char*)lbuf + 16384 + (t2 & 1) * 8192;
      const int  kbase = kmin + t2 * 32;
      const bool peel  = ((q0 >= WIN) && (t2 <= 1)) || (t2 >= nt2 - 2);

      #pragma unroll
      for (int ks = 0; ks < 2; ++ks) {
        f32x4 acc = {0.f, 0.f, 0.f, 0.f};
        const int keyl = ks * 16 + lm;
        PRIO1();
        #pragma unroll
        for (int kb = 0; kb < 4; ++kb) {
          const int chunk = (kb * 4 + lg) ^ (keyl & 7);
          f16x8 bf = *(const f16x8*)(curK + keyl * 256 + chunk * 16);
          acc = __builtin_amdgcn_mfma_f32_16x16x32_f16(qa[kb], bf, acc, 0, 0, 0);
        }
        PRIO0();
        const int key = kbase + keyl;
        #pragma unroll
        for (int r = 0; r < 4; ++r) {
          float wgt = 0.f;
          if (__any(acc[r] > sthr[r])) {
            float e = swa_e(acc[r]);
            wgt = fminf(fmaxf(fmaf(e, rz[r], -0.03f), 0.f), 1.f);
            if (peel) {
              const int qr = qr0 + r;
              const bool ok = (key <= qr) && (key >= qr - WIN);
              wgt = ok ? wgt : 0.f;
            }
          }
          lW[wv][(lg * 4 + r) * WROW + ks * 16 + lm] = (_Float16)wgt;
        }
      }
      // PV over 32 keys: A = W rows, B = V sub-tile rows [d][32], chunk-swizzled
      const f16x8 af = *(const f16x8*)&lW[wv][lm * WROW + lg * 8];
      PRIO1();
      #pragma unroll
      for (int dt = 0; dt < 8; ++dt) {
        const int d = dt * 16 + lm;
        f16x8 bf = *(const f16x8*)(curV + d * 64 + vpc * 16);
        oacc[dt] = __builtin_amdgcn_mfma_f32_16x16x32_f16(af, bf, oacc[dt], 0, 0, 0);
      }
      PRIO0();
      BARP();                                  // readers of buf(t2&1) retired
      if (t2 + 2 < nt2) {
        const int kn = kmin + (t2 + 2) * 32;
        STAGE8K((t2 & 1) * 8192,         kfb + (size_t)kn * DH);
        STAGE8K(16384 + (t2 & 1) * 8192, vtb + (size_t)(kn >> 5) * 8192);
        BARW(4);                               // t2+1 landed, t2+2 in flight
      } else {
        BARW(0);
      }
    }

    // ---- epilogue: D-layout (col=lm is d, row=lg*4+r) -> fp32 out ----
    #pragma unroll
    for (int r = 0; r < 4; ++r) {
      float* op = O + (((size_t)b * SQ + (qr0 + r)) * HQ + h) * DH;
      #pragma unroll
      for (int dt = 0; dt < 8; ++dt) op[dt * 16 + lm] = oacc[dt][r];
    }
  }
  #undef STAGE16K
  #undef STAGE8K
}

extern "C" void kernel_launch(void* const* d_in, const int* in_sizes, int n_in,
                              void* d_out, int out_size, void* d_ws, size_t ws_size,
                              hipStream_t stream) {
  const float* q = (const float*)d_in[0];
  const float* k = (const float*)d_in[1];
  const float* v = (const float*)d_in[2];
  float* o = (float*)d_out;

  _Float16* kf = (_Float16*)d_ws;
  _Float16* vt = kf + (size_t)2 * HKV * SQ * DH;   // 2,097,152 elems each

  hipLaunchKernelGGL(prep, dim3(2048), dim3(256), 0, stream, k, v, kf, vt);
  hipLaunchKernelGGL(swa_fwd, dim3(768), dim3(256), 0, stream, q, o, kf, vt);
}

// Round 19
// 84.590 us; speedup vs baseline: 1.0794x; 1.0794x over previous
//
#include <hip/hip_runtime.h>
#include <hip/hip_bf16.h>

typedef float f32x4 __attribute__((ext_vector_type(4)));
typedef _Float16 f16x8 __attribute__((ext_vector_type(8)));
typedef unsigned int u32;

#define SQ   2048
#define HQ   16
#define HKV  4
#define DH   128
#define WIN  1024
#define QT   64
#define KT   64
#define WROW 36

#define AS1 __attribute__((address_space(1)))
#define AS3 __attribute__((address_space(3)))

__device__ __forceinline__ void gload16(const void* g, void* l) {
  __builtin_amdgcn_global_load_lds((const AS1 u32*)g, (AS3 u32*)l, 16, 0, 0);
}

// fused wait+barrier (verified race-free in round 14)
#define BARW(N) do { __builtin_amdgcn_sched_barrier(0);                        \
  asm volatile("s_waitcnt vmcnt(" #N ")\n\ts_barrier" ::: "memory");           \
  __builtin_amdgcn_sched_barrier(0); } while (0)
#define BARP() do { __builtin_amdgcn_sched_barrier(0);                         \
  asm volatile("s_barrier" ::: "memory");                                      \
  __builtin_amdgcn_sched_barrier(0); } while (0)

#define PRIO1() __builtin_amdgcn_s_setprio(1)
#define PRIO0() __builtin_amdgcn_s_setprio(0)

// e = exp(30*tanh(s/sqrt(128)) - 30) == 2^(-86.5617/(2^(s*0.2550341)+1))
__device__ __forceinline__ float swa_e(float s) {
  float u = __builtin_amdgcn_exp2f(s * 0.2550341464f);
  return __builtin_amdgcn_exp2f(-86.5617025f * __builtin_amdgcn_rcpf(u + 1.0f));
}

// ---- prep: K -> kf f16 row-chunk-swizzled [b][hk][s][d];
//            V -> vt f16 [b][hk][t32][d][key32], chunk c stored at c^((d>>1)&3) ----
__global__ __launch_bounds__(256)
void prep(const float* __restrict__ K, const float* __restrict__ V,
          _Float16* __restrict__ kf, _Float16* __restrict__ vt)
{
  const int t = blockIdx.x * 256 + threadIdx.x;
  const int NK = 2 * HKV * SQ * 16;   // 262144 threads for K
  if (t < NK) {
    const int p  = t & 15;
    const int s  = (t >> 4) & (SQ - 1);
    const int hk = (t >> 15) & 3;
    const int b  = t >> 17;
    const int c  = p ^ (s & 7);
    const float* src = K + (((size_t)b * SQ + s) * HKV + hk) * DH + c * 8;
    f32x4 x0 = *(const f32x4*)src;
    f32x4 x1 = *(const f32x4*)(src + 4);
    f16x8 o;
    #pragma unroll
    for (int j = 0; j < 4; ++j) { o[j] = (_Float16)x0[j]; o[4 + j] = (_Float16)x1[j]; }
    *(f16x8*)(kf + (((size_t)(b * HKV + hk)) * SQ + s) * DH + p * 8) = o;
  } else {
    const int u   = t - NK;                 // 262144 threads for V
    const int p   = u & 3;                  // PHYSICAL 8-key chunk within 32
    const int d   = (u >> 2) & 127;
    const int t32 = (u >> 9) & 63;
    const int hk  = (u >> 15) & 3;
    const int b   = u >> 17;
    const int c   = p ^ ((d >> 1) & 3);     // logical chunk stored at physical p
    f16x8 o;
    #pragma unroll
    for (int j = 0; j < 8; ++j) {
      const int s = t32 * 32 + c * 8 + j;
      o[j] = (_Float16)V[(((size_t)b * SQ + s) * HKV + hk) * DH + d];
    }
    *(f16x8*)(vt + ((((size_t)(b * HKV + hk)) * 64 + t32) * DH + d) * 32 + p * 8) = o;
  }
}

__global__ __launch_bounds__(256, 4)
void swa_fwd(const float* __restrict__ Q, float* __restrict__ O,
             const _Float16* __restrict__ kf, const _Float16* __restrict__ vt)
{
  __shared__ _Float16 lbuf[16384];       // 32KB: ph1 = 2x16KB K; ph2 = K0,K1,V0,V1 x8KB
  __shared__ _Float16 lW[4][16 * WROW];  // 4.6KB

  const int tid  = threadIdx.x;
  const int lane = tid & 63;
  const int wv   = tid >> 6;             // 0..3
  const int lm   = lane & 15;
  const int lg   = lane >> 4;

  // ---- XCD-pinned + CU-balanced quad mapping ----
  const int bid    = blockIdx.x;
  const int stream = bid & 7;
  const int b      = stream >> 2;
  const int hk     = stream & 3;
  const int j      = bid >> 3;           // 0..127
  const int c      = j & 31;
  const int slot   = j >> 5;             // 0..3 (0 = heaviest, dispatched first)
  const int i      = c >> 2;             // 0..7
  const int hs     = c & 3;
  const int qt     = (slot == 0) ? (31 - i) : (slot == 1) ? (16 + i)
                   : (slot == 2) ? (15 - i) : i;
  const int h      = hk * 4 + hs;
  const int q0     = qt * QT;

  const _Float16* kfb = kf + ((size_t)(b * HKV + hk)) * SQ * DH;
  const char*     vtb = (const char*)(vt + ((size_t)(b * HKV + hk)) * 64 * DH * 32);

  // ---- Q fragments (A-layout): row=lm, k=lg*8+j per 32-wide kb ----
  f16x8 qa[4];
  {
    const int qrow = q0 + wv * 16 + lm;
    const float* qp = Q + (((size_t)b * SQ + qrow) * HQ + h) * DH;
    #pragma unroll
    for (int kb = 0; kb < 4; ++kb) {
      const float* p = qp + kb * 32 + lg * 8;
      f32x4 x0 = *(const f32x4*)p;
      f32x4 x1 = *(const f32x4*)(p + 4);
      f16x8 a;
      #pragma unroll
      for (int jj = 0; jj < 4; ++jj) { a[jj] = (_Float16)x0[jj]; a[4 + jj] = (_Float16)x1[jj]; }
      qa[kb] = a;
    }
  }

  const int kmin = (q0 - WIN) > 0 ? (q0 - WIN) : 0;   // multiple of 64
  const int nt   = (q0 + QT - kmin) / KT;             // 1..17
  const int qr0  = q0 + wv * 16 + lg * 4;

  #define STAGE16K(dstb, src) do {                                           \
    _Pragma("unroll")                                                        \
    for (int r4 = 0; r4 < 4; ++r4)                                           \
      gload16((const char*)(src) + r4 * 4096 + wv * 1024 + lane * 16,        \
              (char*)lbuf + (dstb) + r4 * 4096 + wv * 1024);                 \
  } while (0)
  #define STAGE8K(dstb, src) do {                                            \
    _Pragma("unroll")                                                        \
    for (int r2 = 0; r2 < 2; ++r2)                                           \
      gload16((const char*)(src) + r2 * 4096 + wv * 1024 + lane * 16,        \
              (char*)lbuf + (dstb) + r2 * 4096 + wv * 1024);                 \
  } while (0)

  // ============ phase 1: row sums Z (KT=64 K dbuf, counted-vmcnt pipeline) ====
  float zs[4] = {0.f, 0.f, 0.f, 0.f};
  {
    STAGE16K(0, kfb + (size_t)kmin * DH);               // 4 loads/wave
    if (nt > 1) {
      STAGE16K(16384, kfb + (size_t)(kmin + KT) * DH);  // +4
      BARW(4);                                          // t0 landed, t1 in flight
    } else {
      BARW(0);
    }
    for (int t = 0; t < nt; ++t) {
      const char* cur  = (const char*)lbuf + (t & 1) * 16384;
      const int  kbase = kmin + t * KT;
      const bool peel  = (t == 0 && q0 >= WIN) || (t == nt - 1);
      #pragma unroll
      for (int ks = 0; ks < 4; ++ks) {
        f32x4 acc = {0.f, 0.f, 0.f, 0.f};
        const int keyl = ks * 16 + lm;
        PRIO1();
        #pragma unroll
        for (int kb = 0; kb < 4; ++kb) {
          const int chunk = (kb * 4 + lg) ^ (keyl & 7);
          f16x8 bf = *(const f16x8*)(cur + keyl * 256 + chunk * 16);
          acc = __builtin_amdgcn_mfma_f32_16x16x32_f16(qa[kb], bf, acc, 0, 0, 0);
        }
        PRIO0();
        if (peel) {
          const int key = kbase + keyl;
          #pragma unroll
          for (int r = 0; r < 4; ++r) {
            const int qr = qr0 + r;
            const bool ok = (key <= qr) && (key >= qr - WIN);
            zs[r] += ok ? swa_e(acc[r]) : 0.f;
          }
        } else {
          #pragma unroll
          for (int r = 0; r < 4; ++r) zs[r] += swa_e(acc[r]);
        }
      }
      BARP();                                  // all waves' reads of buf(t&1) retired
      if (t + 2 < nt) {
        STAGE16K((t & 1) * 16384, kfb + (size_t)(kmin + (t + 2) * KT) * DH);
        BARW(4);                               // t+1 landed (all waves), t+2 in flight
      } else {
        BARW(0);                               // drain tail
      }
    }
  }

  // ---- Z reduce; rz = 1.06/Z; sthr = survivor threshold in s-space ----
  float rz[4], sthr[4];
  #pragma unroll
  for (int r = 0; r < 4; ++r) {
    float z = zs[r];
    z += __shfl_xor(z, 1);
    z += __shfl_xor(z, 2);
    z += __shfl_xor(z, 4);
    z += __shfl_xor(z, 8);
    rz[r] = 1.06f / z;
    float lt = __log2f(0.0283018868f * z);
    float A  = -86.5617024f / lt - 1.0f;
    float sv = 3.9204912f * __log2f(A) - 0.05f;   // conservative margin
    sv = (lt >= 0.f) ? 1e30f : sv;
    sv = (lt <= -86.5617f) ? -1e30f : sv;
    sthr[r] = sv;
  }

  // ====== phase 2: weights + PV, KT=32 K+V dbuf, counted-vmcnt pipeline ======
  // lbuf bytes: K0 @0, K1 @8192, V0 @16384, V1 @24576
  f32x4 oacc[8];
  #pragma unroll
  for (int ii = 0; ii < 8; ++ii) oacc[ii] = (f32x4){0.f, 0.f, 0.f, 0.f};

  const int nt2 = (q0 + QT - kmin) >> 5;   // 32-key sub-tiles, >= 2
  STAGE8K(0,     kfb + (size_t)kmin * DH);            // K0: 2 loads/wave
  STAGE8K(16384, vtb + (size_t)(kmin >> 5) * 8192);   // V0: 2
  if (nt2 > 1) {
    STAGE8K(8192,         kfb + (size_t)(kmin + 32) * DH);         // K1: 2
    STAGE8K(16384 + 8192, vtb + (size_t)((kmin >> 5) + 1) * 8192); // V1: 2
    BARW(4);                                 // t0's K+V landed, t1's in flight
  } else {
    BARW(0);
  }

  const int vpc = lg ^ ((lm >> 1) & 3);      // physical V chunk for this lane

  for (int t2 = 0; t2 < nt2; ++t2) {
    const char* curK = (const char*)lbuf + (t2 & 1) * 8192;
    const char* curV = (const char*)lbuf + 16384 + (t2 & 1) * 8192;
    const int  kbase = kmin + t2 * 32;
    const bool peel  = ((q0 >= WIN) && (t2 <= 1)) || (t2 >= nt2 - 2);

    #pragma unroll
    for (int ks = 0; ks < 2; ++ks) {
      f32x4 acc = {0.f, 0.f, 0.f, 0.f};
      const int keyl = ks * 16 + lm;
      PRIO1();
      #pragma unroll
      for (int kb = 0; kb < 4; ++kb) {
        const int chunk = (kb * 4 + lg) ^ (keyl & 7);
        f16x8 bf = *(const f16x8*)(curK + keyl * 256 + chunk * 16);
        acc = __builtin_amdgcn_mfma_f32_16x16x32_f16(qa[kb], bf, acc, 0, 0, 0);
      }
      PRIO0();
      const int key = kbase + keyl;
      #pragma unroll
      for (int r = 0; r < 4; ++r) {
        float w = 0.f;
        if (__any(acc[r] > sthr[r])) {
          float e = swa_e(acc[r]);
          w = fminf(fmaxf(fmaf(e, rz[r], -0.03f), 0.f), 1.f);
          if (peel) {
            const int qr = qr0 + r;
            const bool ok = (key <= qr) && (key >= qr - WIN);
            w = ok ? w : 0.f;
          }
        }
        lW[wv][(lg * 4 + r) * WROW + ks * 16 + lm] = (_Float16)w;
      }
    }
    // PV over 32 keys: A = W rows, B = V sub-tile rows [d][32], chunk-swizzled
    const f16x8 af = *(const f16x8*)&lW[wv][lm * WROW + lg * 8];
    PRIO1();
    #pragma unroll
    for (int dt = 0; dt < 8; ++dt) {
      const int d = dt * 16 + lm;
      f16x8 bf = *(const f16x8*)(curV + d * 64 + vpc * 16);
      oacc[dt] = __builtin_amdgcn_mfma_f32_16x16x32_f16(af, bf, oacc[dt], 0, 0, 0);
    }
    PRIO0();
    BARP();                                  // all waves' reads of buf(t2&1) retired
    if (t2 + 2 < nt2) {
      const int kn = kmin + (t2 + 2) * 32;
      STAGE8K((t2 & 1) * 8192,         kfb + (size_t)kn * DH);
      STAGE8K(16384 + (t2 & 1) * 8192, vtb + (size_t)(kn >> 5) * 8192);
      BARW(4);                               // t2+1 landed (all waves), t2+2 in flight
    } else {
      BARW(0);
    }
  }

  // ---- epilogue: D-layout (col=lm is d, row=lg*4+r) -> fp32 out ----
  #pragma unroll
  for (int r = 0; r < 4; ++r) {
    float* op = O + (((size_t)b * SQ + (qr0 + r)) * HQ + h) * DH;
    #pragma unroll
    for (int dt = 0; dt < 8; ++dt) op[dt * 16 + lm] = oacc[dt][r];
  }
  #undef STAGE16K
  #undef STAGE8K
}

extern "C" void kernel_launch(void* const* d_in, const int* in_sizes, int n_in,
                              void* d_out, int out_size, void* d_ws, size_t ws_size,
                              hipStream_t stream) {
  const float* q = (const float*)d_in[0];
  const float* k = (const float*)d_in[1];
  const float* v = (const float*)d_in[2];
  float* o = (float*)d_out;

  _Float16* kf = (_Float16*)d_ws;
  _Float16* vt = kf + (size_t)2 * HKV * SQ * DH;   // 2,097,152 elems each

  hipLaunchKernelGGL(prep, dim3(2048), dim3(256), 0, stream, k, v, kf, vt);
  hipLaunchKernelGGL(swa_fwd, dim3(1024), dim3(256), 0, stream, q, o, kf, vt);
}